// Round 1
// 611.977 us; speedup vs baseline: 1.0511x; 1.0511x over previous
//
#include <hip/hip_runtime.h>
#include <hip/hip_bf16.h>

// Problem constants (B=8, S=4096, D=1024, H=16, hd=64). All I/O is FLOAT32.
#define TOKENS   32768
#define DMODEL   1024
#define THREE_D  3072

using u16 = unsigned short;
typedef __attribute__((ext_vector_type(8))) short short8;  // 8 bf16 = 4 VGPRs
typedef __attribute__((ext_vector_type(4))) float f32x4;

__device__ __forceinline__ float bf2f(u16 u) {
  union { unsigned int i; float f; } v; v.i = ((unsigned int)u) << 16; return v.f;
}
__device__ __forceinline__ u16 f2bf(float f) {
  __hip_bfloat16 h = __float2bfloat16(f);   // RNE
  return *reinterpret_cast<u16*>(&h);
}

// async global->LDS, 16B per lane; LDS dest = wave-uniform base + lane*16
__device__ __forceinline__ void gload_lds16(const u16* g, u16* l) {
  __builtin_amdgcn_global_load_lds((const __attribute__((address_space(1))) void*)g,
                                   (__attribute__((address_space(3))) void*)l,
                                   16, 0, 0);
}

// ---------------------------------------------------------------------------
// f32 -> bf16 elementwise convert (n divisible by 1024)
// ---------------------------------------------------------------------------
__global__ __launch_bounds__(256) void convert_f32_bf16(const float* __restrict__ in,
                                                        u16* __restrict__ out, long n) {
  long i = ((long)blockIdx.x * 256 + threadIdx.x) * 4;
  if (i >= n) return;
  float4 v = *reinterpret_cast<const float4*>(in + i);
  ushort4 o;
  o.x = f2bf(v.x); o.y = f2bf(v.y); o.z = f2bf(v.z); o.w = f2bf(v.w);
  *reinterpret_cast<ushort4*>(out + i) = o;
}

// ---------------------------------------------------------------------------
// f32 in (R x C) -> bf16 out (C x R) transpose+convert. R, C multiples of 32.
// ---------------------------------------------------------------------------
__global__ __launch_bounds__(256) void transpose_convert(const float* __restrict__ in,
                                                         u16* __restrict__ out,
                                                         int R, int C) {
  __shared__ u16 tile[32][33];
  const int bc = blockIdx.x * 32;
  const int br = blockIdx.y * 32;
  const int tx = threadIdx.x & 31;
  const int ty = threadIdx.x >> 5;
  #pragma unroll
  for (int i = 0; i < 32; i += 8)
    tile[ty + i][tx] = f2bf(in[(long)(br + ty + i) * C + bc + tx]);
  __syncthreads();
  #pragma unroll
  for (int i = 0; i < 32; i += 8)
    out[(long)(bc + ty + i) * R + br + tx] = tile[tx][ty + i];
}

// ---------------------------------------------------------------------------
// C(M,N) = A(M,K) @ BT(N,K)^T + bias(N).  A,BT bf16; bias f32; MFMA f32 acc.
// 256x256 tile, 8 waves (512 thr), BK=64, 8-phase counted-vmcnt schedule
// (T1+T2+T3+T4+T5).  LDS 128 KiB: As[2][256*64], Bs[2][256*64], tile parity
// selects buffer.  Per iteration: 2 K-tiles, 8 phases; each phase = {ds_read
// frags, stage 1 half-region (2 gload_lds), [vmcnt(4) at p4/p8], s_barrier,
// lgkmcnt(0), setprio(1), 16 MFMA, setprio(0), s_barrier}.  vmcnt never
// drained to 0 in the main loop.
//
// Quadrant order per K-tile: (Qr,Qc) = (0,0),(0,1),(1,1),(1,0) so each
// half-region's last read is as early as possible:
//   A0 retires after q2, B1 after q3, A1+B0 after q4.
// Stage stream (verified hazard-free; stage of region X always issued after
// the barrier following X's last read, and every read covered by a prior
// vmcnt(4) that keeps exactly the last 2 half-stages (4 loads) in flight):
//   p1: A1[t+1]  p2: B0[t+1]  p3: A0[t+2]  p4: B1[t+2] +vmcnt(4)
//   p5: A1[t+2]  p6: B0[t+2]  p7: A0[t+3]  p8: B1[t+3] +vmcnt(4)
//
// XOR chunk swizzle (measured 0 bank conflicts in the 128B-row layout):
// staging lane L covers row base+(L>>3), phys chunk (L&7), loading GLOBAL
// chunk (L&7)^(L>>3); reads fetch global chunk c of row r at phys c^(r&7).
//
// A read through column remap: logical col c -> row*a_stride + (c>>6)*a_grp
// + (c&63).  Identity: a_stride=K, a_grp=64.  M%256==0, N%256==0, K%128==0.
// ---------------------------------------------------------------------------
#define BM 256
#define BN 256
#define BK 64

#define VM4 asm volatile("s_waitcnt vmcnt(4)" ::: "memory")
#define VM0 asm volatile("s_waitcnt vmcnt(0)" ::: "memory")
#define VMN ((void)0)
#define NOSTAGE ((void)0)

// stage one 128-row half of A or B for K-tile T into buffer (T&1)
#define STAGE_A(T, H)                                                          \
  { _Pragma("unroll") for (int j_ = 0; j_ < 2; j_++) {                         \
      const int lr_ = (H) * 128 + (wave * 2 + j_) * 8;                         \
      gload_lds16(A + (long)(bm + lr_ + sr) * a_stride + (long)(T) * a_grp + scol, \
                  &As[(T) & 1][lr_ * BK]);                                     \
  } }
#define STAGE_B(T, H)                                                          \
  { _Pragma("unroll") for (int j_ = 0; j_ < 2; j_++) {                         \
      const int lr_ = (H) * 128 + (wave * 2 + j_) * 8;                         \
      gload_lds16(BT + (long)(bn + lr_ + sr) * K + (T) * BK + scol,            \
                  &Bs[(T) & 1][lr_ * BK]);                                     \
  } }

// one phase: quadrant (QR,QC) of the buffer-BUF K-tile.
// RDA=1 re-reads the A frags (shared by the (QR,0)/(QR,1) phase pair).
#define PHASE(BUF, QR, QC, RDA, STAGE, VMW)                                    \
  {                                                                            \
    if (RDA) {                                                                 \
      _Pragma("unroll") for (int mi = 0; mi < 2; mi++)                         \
        _Pragma("unroll") for (int kh = 0; kh < 2; kh++)                       \
          a[mi][kh] = *reinterpret_cast<const short8*>(                        \
              &As[BUF][((QR) * 128 + wrow + mi * 16 + lrow) * BK +             \
                       (((kh * 4 + quad) ^ xs) * 8)]);                         \
    }                                                                          \
    short8 b[4][2];                                                            \
    _Pragma("unroll") for (int ni = 0; ni < 4; ni++)                           \
      _Pragma("unroll") for (int kh = 0; kh < 2; kh++)                         \
        b[ni][kh] = *reinterpret_cast<const short8*>(                          \
            &Bs[BUF][((QC) * 128 + wcol + ni * 16 + lrow) * BK +               \
                     (((kh * 4 + quad) ^ xs) * 8)]);                           \
    STAGE;                                                                     \
    VMW;                                                                       \
    __builtin_amdgcn_s_barrier();                                              \
    asm volatile("s_waitcnt lgkmcnt(0)" ::: "memory");                         \
    __builtin_amdgcn_sched_barrier(0);                                         \
    __builtin_amdgcn_s_setprio(1);                                             \
    _Pragma("unroll") for (int mi = 0; mi < 2; mi++)                           \
      _Pragma("unroll") for (int ni = 0; ni < 4; ni++) {                       \
        acc[QR][QC][mi][ni] = __builtin_amdgcn_mfma_f32_16x16x32_bf16(         \
            a[mi][0], b[ni][0], acc[QR][QC][mi][ni], 0, 0, 0);                 \
        acc[QR][QC][mi][ni] = __builtin_amdgcn_mfma_f32_16x16x32_bf16(         \
            a[mi][1], b[ni][1], acc[QR][QC][mi][ni], 0, 0, 0);                 \
      }                                                                        \
    __builtin_amdgcn_s_setprio(0);                                             \
    __builtin_amdgcn_s_barrier();                                              \
    __builtin_amdgcn_sched_barrier(0);                                         \
  }

template <bool OUT_F32>
__global__ __launch_bounds__(512, 2) void gemm_bt_bias(
    const u16* __restrict__ A, const u16* __restrict__ BT,
    const float* __restrict__ bias, void* __restrict__ Cv,
    int M, int N, int K, long a_stride, int a_grp) {
  __shared__ alignas(16) u16 As[2][BM * BK];  // 64 KB
  __shared__ alignas(16) u16 Bs[2][BN * BK];  // 64 KB
  (void)M;

  // XCD-aware bijective swizzle (gridDim.x % 8 == 0 for our shapes):
  // XCD x gets a contiguous chunk of logical tiles -> per-XCD L2 locality.
  const int cpx = gridDim.x >> 3;
  const int wg  = ((int)blockIdx.x & 7) * cpx + ((int)blockIdx.x >> 3);
  const int tiles_n = N / BN;
  const int bm = (wg / tiles_n) * BM;
  const int bn = (wg % tiles_n) * BN;

  const int tid  = threadIdx.x;
  const int wave = tid >> 6;           // 0..7
  const int lane = tid & 63;
  const int wrow = (wave & 3) * 32;    // row slice within a 128-row quadrant
  const int wcol = (wave >> 2) * 64;   // col slice within a 128-col quadrant
  const int lrow = lane & 15;
  const int quad = lane >> 4;
  const int xs   = lrow & 7;

  // staging lane decomposition
  const int sr     = lane >> 3;              // row within 8-row group
  const int schunk = (lane & 7) ^ sr;        // GLOBAL 16B chunk this lane loads
  const int scol   = schunk * 8;

  const int NT = K / BK;   // even, >= 4

  f32x4 acc[2][2][2][4];
  #pragma unroll
  for (int i = 0; i < 2; i++)
    #pragma unroll
    for (int j = 0; j < 2; j++)
      #pragma unroll
      for (int m = 0; m < 2; m++)
        #pragma unroll
        for (int n = 0; n < 4; n++) acc[i][j][m][n] = (f32x4){0.f, 0.f, 0.f, 0.f};

  // prologue: tile0 fully (8 loads), then tile1's A0,B1 (4 loads).
  // vmcnt(4) -> tile0 landed, tile1's pair may float.
  STAGE_A(0, 0); STAGE_A(0, 1); STAGE_B(0, 0); STAGE_B(0, 1);
  STAGE_A(1, 0); STAGE_B(1, 1);
  VM4;
  __builtin_amdgcn_s_barrier();

  short8 a[2][2];
  #pragma unroll 1
  for (int t = 0; t + 2 < NT; t += 2) {
    PHASE(0, 0, 0, 1, STAGE_A(t + 1, 1), VMN);
    PHASE(0, 0, 1, 0, STAGE_B(t + 1, 0), VMN);
    PHASE(0, 1, 1, 1, STAGE_A(t + 2, 0), VMN);
    PHASE(0, 1, 0, 0, STAGE_B(t + 2, 1), VM4);   // tile t+1 now complete
    PHASE(1, 0, 0, 1, STAGE_A(t + 2, 1), VMN);
    PHASE(1, 0, 1, 0, STAGE_B(t + 2, 0), VMN);
    PHASE(1, 1, 1, 1, STAGE_A(t + 3, 0), VMN);
    PHASE(1, 1, 0, 0, STAGE_B(t + 3, 1), VM4);   // tile t+2 now complete
  }
  // peeled last iteration (t = NT-2): only tile NT-1's A1,B0 remain to stage.
  PHASE(0, 0, 0, 1, STAGE_A(NT - 1, 1), VMN);
  PHASE(0, 0, 1, 0, STAGE_B(NT - 1, 0), VMN);
  PHASE(0, 1, 1, 1, NOSTAGE, VMN);
  PHASE(0, 1, 0, 0, NOSTAGE, VM0);               // tail drain (once per block)
  PHASE(1, 0, 0, 1, NOSTAGE, VMN);
  PHASE(1, 0, 1, 0, NOSTAGE, VMN);
  PHASE(1, 1, 1, 1, NOSTAGE, VMN);
  PHASE(1, 1, 0, 0, NOSTAGE, VMN);

  // epilogue: C/D layout col = lane&15, row = (lane>>4)*4 + r
  #pragma unroll
  for (int qc = 0; qc < 2; qc++) {
    #pragma unroll
    for (int ni = 0; ni < 4; ni++) {
      const int col = bn + qc * 128 + wcol + ni * 16 + lrow;
      const float bv = bias[col];
      #pragma unroll
      for (int qr = 0; qr < 2; qr++) {
        #pragma unroll
        for (int mi = 0; mi < 2; mi++) {
          #pragma unroll
          for (int r = 0; r < 4; r++) {
            const int row = bm + qr * 128 + wrow + mi * 16 + quad * 4 + r;
            const float val = acc[qr][qc][mi][ni][r] + bv;
            if (OUT_F32)
              ((float*)Cv)[(long)row * N + col] = val;
            else
              ((u16*)Cv)[(long)row * N + col] = f2bf(val);
          }
        }
      }
    }
  }
}

// ---------------------------------------------------------------------------
// Per-token attention across the 16 heads. One wave per token. (unchanged)
// ---------------------------------------------------------------------------
__global__ __launch_bounds__(256) void attn_local(u16* __restrict__ qkv) {
  __shared__ float p_s[4][16][16];
  const int tid  = threadIdx.x;
  const int wave = tid >> 6;
  const int lane = tid & 63;
  const int t    = blockIdx.x * 4 + wave;
  u16* row = qkv + (long)t * THREE_D;
  const int lrow = lane & 15;
  const int quad = lane >> 4;
  const int kq   = quad * 8;

  short8 a0 = *reinterpret_cast<const short8*>(row + lrow * 192 + kq);
  short8 a1 = *reinterpret_cast<const short8*>(row + lrow * 192 + 32 + kq);
  short8 b0 = *reinterpret_cast<const short8*>(row + lrow * 192 + 64 + kq);
  short8 b1 = *reinterpret_cast<const short8*>(row + lrow * 192 + 96 + kq);
  f32x4 s = {0.f, 0.f, 0.f, 0.f};
  s = __builtin_amdgcn_mfma_f32_16x16x32_bf16(a0, b0, s, 0, 0, 0);
  s = __builtin_amdgcn_mfma_f32_16x16x32_bf16(a1, b1, s, 0, 0, 0);

  const float scale = 0.125f;  // 1/sqrt(64)
  float p[4];
  #pragma unroll
  for (int r = 0; r < 4; r++) {
    float x = s[r] * scale;
    float m = x;
    #pragma unroll
    for (int mask = 1; mask < 16; mask <<= 1) m = fmaxf(m, __shfl_xor(m, mask));
    float e = __expf(x - m);
    float l = e;
    #pragma unroll
    for (int mask = 1; mask < 16; mask <<= 1) l += __shfl_xor(l, mask);
    p[r] = e / l;
  }
  #pragma unroll
  for (int r = 0; r < 4; r++) p_s[wave][quad * 4 + r][lrow] = p[r];
  __syncthreads();

  float o[16];
  #pragma unroll
  for (int i = 0; i < 16; i++) o[i] = 0.f;
  #pragma unroll
  for (int j = 0; j < 16; j++) {
    float vj = bf2f(row[j * 192 + 128 + lane]);
    #pragma unroll
    for (int i = 0; i < 16; i++) o[i] += p_s[wave][i][j] * vj;
  }
  #pragma unroll
  for (int i = 0; i < 16; i++)
    row[i * 192 + lane] = f2bf(o[i]);
}

// ---------------------------------------------------------------------------
extern "C" void kernel_launch(void* const* d_in, const int* in_sizes, int n_in,
                              void* d_out, int out_size, void* d_ws, size_t ws_size,
                              hipStream_t stream) {
  const float* x     = (const float*)d_in[0];  // (T, 1024) f32
  const float* W_qkv = (const float*)d_in[1];  // (1024, 3072) f32
  const float* b_qkv = (const float*)d_in[2];  // (3072) f32
  const float* W_out = (const float*)d_in[3];  // (1024, 1024) f32
  const float* b_out = (const float*)d_in[4];  // (1024) f32
  float* out = (float*)d_out;                  // (T, 1024) f32

  char* ws = (char*)d_ws;
  u16* qkv   = (u16*)ws;  ws += (size_t)TOKENS * THREE_D * 2;   // 192 MiB
  u16* x_bf  = (u16*)ws;  ws += (size_t)TOKENS * DMODEL * 2;    //  64 MiB
  u16* wqkvT = (u16*)ws;  ws += (size_t)THREE_D * DMODEL * 2;   //   6 MiB
  u16* woutT = (u16*)ws;                                        //   2 MiB

  dim3 tb(256);
  dim3 gtb(512);
  convert_f32_bf16<<<dim3((TOKENS * DMODEL) / 1024), tb, 0, stream>>>(
      x, x_bf, (long)TOKENS * DMODEL);
  transpose_convert<<<dim3(THREE_D / 32, DMODEL / 32), tb, 0, stream>>>(W_qkv, wqkvT, DMODEL, THREE_D);
  transpose_convert<<<dim3(DMODEL / 32, DMODEL / 32), tb, 0, stream>>>(W_out, woutT, DMODEL, DMODEL);
  // GEMM1: qkv = x @ W_qkv + b_qkv   (bf16 out, identity A-map)  grid=1536
  gemm_bt_bias<false><<<dim3((TOKENS / BM) * (THREE_D / BN)), gtb, 0, stream>>>(
      x_bf, wqkvT, b_qkv, qkv, TOKENS, THREE_D, DMODEL, (long)DMODEL, 64);
  // attention (in place: output -> q-slots of qkv)
  attn_local<<<dim3(TOKENS / 4), tb, 0, stream>>>(qkv);
  // GEMM2: out = vals @ W_out + b_out  (f32 out; A = q-slots: stride 3072, group 192)  grid=512
  gemm_bt_bias<true><<<dim3((TOKENS / BM) * (DMODEL / BN)), gtb, 0, stream>>>(
      qkv, woutT, b_out, out, TOKENS, DMODEL, DMODEL, (long)THREE_D, 192);
}

// Round 2
// 599.604 us; speedup vs baseline: 1.0728x; 1.0206x over previous
//
#include <hip/hip_runtime.h>
#include <hip/hip_bf16.h>

// Problem constants (B=8, S=4096, D=1024, H=16, hd=64). All I/O is FLOAT32.
#define TOKENS   32768
#define DMODEL   1024
#define THREE_D  3072

using u16 = unsigned short;
typedef __attribute__((ext_vector_type(8))) short short8;  // 8 bf16 = 4 VGPRs
typedef __attribute__((ext_vector_type(4))) float f32x4;

__device__ __forceinline__ float bf2f(u16 u) {
  union { unsigned int i; float f; } v; v.i = ((unsigned int)u) << 16; return v.f;
}
__device__ __forceinline__ u16 f2bf(float f) {
  __hip_bfloat16 h = __float2bfloat16(f);   // RNE
  return *reinterpret_cast<u16*>(&h);
}

// async global->LDS, 16B per lane; LDS dest = wave-uniform base + lane*16
__device__ __forceinline__ void gload_lds16(const u16* g, u16* l) {
  __builtin_amdgcn_global_load_lds((const __attribute__((address_space(1))) void*)g,
                                   (__attribute__((address_space(3))) void*)l,
                                   16, 0, 0);
}

// ---------------------------------------------------------------------------
// f32 -> bf16 elementwise convert (n divisible by 1024)
// ---------------------------------------------------------------------------
__global__ __launch_bounds__(256) void convert_f32_bf16(const float* __restrict__ in,
                                                        u16* __restrict__ out, long n) {
  long i = ((long)blockIdx.x * 256 + threadIdx.x) * 4;
  if (i >= n) return;
  float4 v = *reinterpret_cast<const float4*>(in + i);
  ushort4 o;
  o.x = f2bf(v.x); o.y = f2bf(v.y); o.z = f2bf(v.z); o.w = f2bf(v.w);
  *reinterpret_cast<ushort4*>(out + i) = o;
}

// ---------------------------------------------------------------------------
// f32 in (R x C) -> bf16 out (C x R) transpose+convert. R, C multiples of 32.
// ---------------------------------------------------------------------------
__global__ __launch_bounds__(256) void transpose_convert(const float* __restrict__ in,
                                                         u16* __restrict__ out,
                                                         int R, int C) {
  __shared__ u16 tile[32][33];
  const int bc = blockIdx.x * 32;
  const int br = blockIdx.y * 32;
  const int tx = threadIdx.x & 31;
  const int ty = threadIdx.x >> 5;
  #pragma unroll
  for (int i = 0; i < 32; i += 8)
    tile[ty + i][tx] = f2bf(in[(long)(br + ty + i) * C + bc + tx]);
  __syncthreads();
  #pragma unroll
  for (int i = 0; i < 32; i += 8)
    out[(long)(bc + ty + i) * R + br + tx] = tile[tx][ty + i];
}

// ---------------------------------------------------------------------------
// C(M,N) = A(M,K) @ BT(N,K)^T + bias(N).  A,BT bf16; bias f32; MFMA f32 acc.
// 256x256 tile, 8 waves (512 thr), BK=64, 8-phase counted-vmcnt schedule.
// LDS 128 KiB: As[2][256*64], Bs[2][256*64]; buffer = tile parity.
//
// Quadrant order per K-tile: (QR,QC) = (0,0),(1,0),(1,1),(0,1).
//  - B fragments (8 x b128) are read once per QC and HELD in registers across
//    the QC-sharing phase pair (RDB flag).  A fragments (4 x b128) read per
//    QR, held across the QR-sharing pair (p2->p3), re-read once at p4.
//  - ds_read count: 12,4,8,4 per phase = 28/K-tile (was 40).
//
// LDS-region retirement (last ds_read): B0 after p1, A1 after p2, B1 after
// p3, A0 after p4 (re-read).  Stage slots land only in retired regions, each
// >= 1 barrier after the last read, and >= 4 phases before first use:
//   p1: A0[t+1]  p2: B0[t+2]  p3: A1[t+2]  p4: B1[t+2] +vmcnt(6)
//   p5: A0[t+2]  p6: B0[t+3]  p7: A1[t+3]  p8: B1[t+3] +vmcnt(6)
// vmcnt(6) (2 loads/phase, newest 3 phases float) covers every read: the
// youngest load any upcoming phase depends on is always >= 7th-newest.
// vmcnt never drains to 0 in the main loop (once in the peel).
//
// XOR chunk swizzle (0 bank conflicts, measured): staging lane L covers row
// base+(L>>3), phys 16B chunk (L&7), loading GLOBAL chunk (L&7)^(L>>3);
// reads fetch global chunk c of row r at phys c^(r&7).
//
// A read through column remap: logical col c -> row*a_stride + (c>>6)*a_grp
// + (c&63).  Identity: a_stride=K, a_grp=64.  M%256==0, N%256==0,
// K%128==0 (NT even, >= 4).
// ---------------------------------------------------------------------------
#define BM 256
#define BN 256
#define BK 64

#define VM6 asm volatile("s_waitcnt vmcnt(6)" ::: "memory")
#define VM0 asm volatile("s_waitcnt vmcnt(0)" ::: "memory")
#define VMN ((void)0)
#define NOSTAGE ((void)0)

// stage one 128-row half (H) of A or B for K-tile T into buffer (T&1)
#define STAGE_A(T, H)                                                          \
  { _Pragma("unroll") for (int j_ = 0; j_ < 2; j_++) {                         \
      const int lr_ = (H) * 128 + (wave * 2 + j_) * 8;                         \
      gload_lds16(A + (long)(bm + lr_ + sr) * a_stride + (long)(T) * a_grp + scol, \
                  &As[(T) & 1][lr_ * BK]);                                     \
  } }
#define STAGE_B(T, H)                                                          \
  { _Pragma("unroll") for (int j_ = 0; j_ < 2; j_++) {                         \
      const int lr_ = (H) * 128 + (wave * 2 + j_) * 8;                         \
      gload_lds16(BT + (long)(bn + lr_ + sr) * K + (T) * BK + scol,            \
                  &Bs[(T) & 1][lr_ * BK]);                                     \
  } }

// one phase: quadrant (QR,QC) of the buffer-BUF K-tile.
// RDA/RDB: refresh the A/B register fragments (else reuse previous phase's).
#define PHASE(BUF, QR, QC, RDA, RDB, STAGE, VMW)                               \
  {                                                                            \
    if (RDA) {                                                                 \
      _Pragma("unroll") for (int mi = 0; mi < 2; mi++)                         \
        _Pragma("unroll") for (int kh = 0; kh < 2; kh++)                       \
          a[mi][kh] = *reinterpret_cast<const short8*>(                        \
              &As[BUF][((QR) * 128 + wrow + mi * 16 + lrow) * BK +             \
                       (((kh * 4 + quad) ^ xs) * 8)]);                         \
    }                                                                          \
    if (RDB) {                                                                 \
      _Pragma("unroll") for (int ni = 0; ni < 4; ni++)                         \
        _Pragma("unroll") for (int kh = 0; kh < 2; kh++)                       \
          b[ni][kh] = *reinterpret_cast<const short8*>(                        \
              &Bs[BUF][((QC) * 128 + wcol + ni * 16 + lrow) * BK +             \
                       (((kh * 4 + quad) ^ xs) * 8)]);                         \
    }                                                                          \
    STAGE;                                                                     \
    VMW;                                                                       \
    __builtin_amdgcn_s_barrier();                                              \
    asm volatile("s_waitcnt lgkmcnt(0)" ::: "memory");                         \
    __builtin_amdgcn_sched_barrier(0);                                         \
    __builtin_amdgcn_s_setprio(1);                                             \
    _Pragma("unroll") for (int mi = 0; mi < 2; mi++)                           \
      _Pragma("unroll") for (int ni = 0; ni < 4; ni++) {                       \
        acc[QR][QC][mi][ni] = __builtin_amdgcn_mfma_f32_16x16x32_bf16(         \
            a[mi][0], b[ni][0], acc[QR][QC][mi][ni], 0, 0, 0);                 \
        acc[QR][QC][mi][ni] = __builtin_amdgcn_mfma_f32_16x16x32_bf16(         \
            a[mi][1], b[ni][1], acc[QR][QC][mi][ni], 0, 0, 0);                 \
      }                                                                        \
    __builtin_amdgcn_s_setprio(0);                                             \
    __builtin_amdgcn_s_barrier();                                              \
    __builtin_amdgcn_sched_barrier(0);                                         \
  }

template <bool OUT_F32>
__global__ __launch_bounds__(512, 2) void gemm_bt_bias(
    const u16* __restrict__ A, const u16* __restrict__ BT,
    const float* __restrict__ bias, void* __restrict__ Cv,
    int M, int N, int K, long a_stride, int a_grp) {
  __shared__ alignas(16) u16 As[2][BM * BK];  // 64 KB
  __shared__ alignas(16) u16 Bs[2][BN * BK];  // 64 KB
  (void)M;

  // XCD-aware bijective swizzle (gridDim.x % 8 == 0 for our shapes)
  const int cpx = gridDim.x >> 3;
  const int wg  = ((int)blockIdx.x & 7) * cpx + ((int)blockIdx.x >> 3);
  const int tiles_n = N / BN;
  const int bm = (wg / tiles_n) * BM;
  const int bn = (wg % tiles_n) * BN;

  const int tid  = threadIdx.x;
  const int wave = tid >> 6;           // 0..7
  const int lane = tid & 63;
  const int wrow = (wave & 3) * 32;    // row slice within a 128-row quadrant
  const int wcol = (wave >> 2) * 64;   // col slice within a 128-col quadrant
  const int lrow = lane & 15;
  const int quad = lane >> 4;
  const int xs   = lrow & 7;

  // staging lane decomposition
  const int sr     = lane >> 3;              // row within 8-row group
  const int schunk = (lane & 7) ^ sr;        // GLOBAL 16B chunk this lane loads
  const int scol   = schunk * 8;

  const int NT = K / BK;   // even, >= 4

  f32x4 acc[2][2][2][4];
  #pragma unroll
  for (int i = 0; i < 2; i++)
    #pragma unroll
    for (int j = 0; j < 2; j++)
      #pragma unroll
      for (int m = 0; m < 2; m++)
        #pragma unroll
        for (int n = 0; n < 4; n++) acc[i][j][m][n] = (f32x4){0.f, 0.f, 0.f, 0.f};

  // prologue: tile0 fully (8 loads) + tile1's B0,A1,B1 (6 loads).
  // vmcnt(6) -> tile0 landed, tile1's three halves float (steady-state entry:
  // 6 outstanding; p1 will stage the missing A0[1]).
  STAGE_A(0, 0); STAGE_B(0, 0); STAGE_A(0, 1); STAGE_B(0, 1);
  STAGE_B(1, 0); STAGE_A(1, 1); STAGE_B(1, 1);
  VM6;
  __builtin_amdgcn_s_barrier();

  short8 a[2][2];
  short8 b[4][2];
  #pragma unroll 1
  for (int t = 0; t + 3 < NT; t += 2) {
    PHASE(0, 0, 0, 1, 1, STAGE_A(t + 1, 0), VMN);   // p1
    PHASE(0, 1, 0, 1, 0, STAGE_B(t + 2, 0), VMN);   // p2
    PHASE(0, 1, 1, 0, 1, STAGE_A(t + 2, 1), VMN);   // p3
    PHASE(0, 0, 1, 1, 0, STAGE_B(t + 2, 1), VM6);   // p4: tile t+1 covered
    PHASE(1, 0, 0, 1, 1, STAGE_A(t + 2, 0), VMN);   // p5
    PHASE(1, 1, 0, 1, 0, STAGE_B(t + 3, 0), VMN);   // p6
    PHASE(1, 1, 1, 0, 1, STAGE_A(t + 3, 1), VMN);   // p7
    PHASE(1, 0, 1, 1, 0, STAGE_B(t + 3, 1), VM6);   // p8: tile t+2 covered
  }
  // peeled last pair (t = NT-2, NT-1): only A0[NT-1] remains to stage.
  PHASE(0, 0, 0, 1, 1, STAGE_A(NT - 1, 0), VMN);
  PHASE(0, 1, 0, 1, 0, NOSTAGE, VMN);
  PHASE(0, 1, 1, 0, 1, NOSTAGE, VMN);
  PHASE(0, 0, 1, 1, 0, NOSTAGE, VM0);               // tail drain (once)
  PHASE(1, 0, 0, 1, 1, NOSTAGE, VMN);
  PHASE(1, 1, 0, 1, 0, NOSTAGE, VMN);
  PHASE(1, 1, 1, 0, 1, NOSTAGE, VMN);
  PHASE(1, 0, 1, 1, 0, NOSTAGE, VMN);

  // epilogue: C/D layout col = lane&15, row = (lane>>4)*4 + r
  #pragma unroll
  for (int qc = 0; qc < 2; qc++) {
    #pragma unroll
    for (int ni = 0; ni < 4; ni++) {
      const int col = bn + qc * 128 + wcol + ni * 16 + lrow;
      const float bv = bias[col];
      #pragma unroll
      for (int qr = 0; qr < 2; qr++) {
        #pragma unroll
        for (int mi = 0; mi < 2; mi++) {
          #pragma unroll
          for (int r = 0; r < 4; r++) {
            const int row = bm + qr * 128 + wrow + mi * 16 + quad * 4 + r;
            const float val = acc[qr][qc][mi][ni][r] + bv;
            if (OUT_F32)
              ((float*)Cv)[(long)row * N + col] = val;
            else
              ((u16*)Cv)[(long)row * N + col] = f2bf(val);
          }
        }
      }
    }
  }
}

// ---------------------------------------------------------------------------
// Per-token attention across the 16 heads. One wave per token. (unchanged)
// ---------------------------------------------------------------------------
__global__ __launch_bounds__(256) void attn_local(u16* __restrict__ qkv) {
  __shared__ float p_s[4][16][16];
  const int tid  = threadIdx.x;
  const int wave = tid >> 6;
  const int lane = tid & 63;
  const int t    = blockIdx.x * 4 + wave;
  u16* row = qkv + (long)t * THREE_D;
  const int lrow = lane & 15;
  const int quad = lane >> 4;
  const int kq   = quad * 8;

  short8 a0 = *reinterpret_cast<const short8*>(row + lrow * 192 + kq);
  short8 a1 = *reinterpret_cast<const short8*>(row + lrow * 192 + 32 + kq);
  short8 b0 = *reinterpret_cast<const short8*>(row + lrow * 192 + 64 + kq);
  short8 b1 = *reinterpret_cast<const short8*>(row + lrow * 192 + 96 + kq);
  f32x4 s = {0.f, 0.f, 0.f, 0.f};
  s = __builtin_amdgcn_mfma_f32_16x16x32_bf16(a0, b0, s, 0, 0, 0);
  s = __builtin_amdgcn_mfma_f32_16x16x32_bf16(a1, b1, s, 0, 0, 0);

  const float scale = 0.125f;  // 1/sqrt(64)
  float p[4];
  #pragma unroll
  for (int r = 0; r < 4; r++) {
    float x = s[r] * scale;
    float m = x;
    #pragma unroll
    for (int mask = 1; mask < 16; mask <<= 1) m = fmaxf(m, __shfl_xor(m, mask));
    float e = __expf(x - m);
    float l = e;
    #pragma unroll
    for (int mask = 1; mask < 16; mask <<= 1) l += __shfl_xor(l, mask);
    p[r] = e / l;
  }
  #pragma unroll
  for (int r = 0; r < 4; r++) p_s[wave][quad * 4 + r][lrow] = p[r];
  __syncthreads();

  float o[16];
  #pragma unroll
  for (int i = 0; i < 16; i++) o[i] = 0.f;
  #pragma unroll
  for (int j = 0; j < 16; j++) {
    float vj = bf2f(row[j * 192 + 128 + lane]);
    #pragma unroll
    for (int i = 0; i < 16; i++) o[i] += p_s[wave][i][j] * vj;
  }
  #pragma unroll
  for (int i = 0; i < 16; i++)
    row[i * 192 + lane] = f2bf(o[i]);
}

// ---------------------------------------------------------------------------
extern "C" void kernel_launch(void* const* d_in, const int* in_sizes, int n_in,
                              void* d_out, int out_size, void* d_ws, size_t ws_size,
                              hipStream_t stream) {
  const float* x     = (const float*)d_in[0];  // (T, 1024) f32
  const float* W_qkv = (const float*)d_in[1];  // (1024, 3072) f32
  const float* b_qkv = (const float*)d_in[2];  // (3072) f32
  const float* W_out = (const float*)d_in[3];  // (1024, 1024) f32
  const float* b_out = (const float*)d_in[4];  // (1024) f32
  float* out = (float*)d_out;                  // (T, 1024) f32

  char* ws = (char*)d_ws;
  u16* qkv   = (u16*)ws;  ws += (size_t)TOKENS * THREE_D * 2;   // 192 MiB
  u16* x_bf  = (u16*)ws;  ws += (size_t)TOKENS * DMODEL * 2;    //  64 MiB
  u16* wqkvT = (u16*)ws;  ws += (size_t)THREE_D * DMODEL * 2;   //   6 MiB
  u16* woutT = (u16*)ws;                                        //   2 MiB

  dim3 tb(256);
  dim3 gtb(512);
  convert_f32_bf16<<<dim3((TOKENS * DMODEL) / 1024), tb, 0, stream>>>(
      x, x_bf, (long)TOKENS * DMODEL);
  transpose_convert<<<dim3(THREE_D / 32, DMODEL / 32), tb, 0, stream>>>(W_qkv, wqkvT, DMODEL, THREE_D);
  transpose_convert<<<dim3(DMODEL / 32, DMODEL / 32), tb, 0, stream>>>(W_out, woutT, DMODEL, DMODEL);
  // GEMM1: qkv = x @ W_qkv + b_qkv   (bf16 out, identity A-map)  grid=1536
  gemm_bt_bias<false><<<dim3((TOKENS / BM) * (THREE_D / BN)), gtb, 0, stream>>>(
      x_bf, wqkvT, b_qkv, qkv, TOKENS, THREE_D, DMODEL, (long)DMODEL, 64);
  // attention (in place: output -> q-slots of qkv)
  attn_local<<<dim3(TOKENS / 4), tb, 0, stream>>>(qkv);
  // GEMM2: out = vals @ W_out + b_out  (f32 out; A = q-slots)  grid=512
  gemm_bt_bias<true><<<dim3((TOKENS / BM) * (DMODEL / BN)), gtb, 0, stream>>>(
      qkv, woutT, b_out, out, TOKENS, DMODEL, DMODEL, (long)THREE_D, 192);
}